// Round 9
// baseline (268.808 us; speedup 1.0000x reference)
//
#include <hip/hip_runtime.h>
#include <math.h>

namespace {

constexpr int kB = 4, kN = 512, kC = 256, kH = 8, kDG = 6, kHID = 16;

// LDS strides (uints/floats). b128 reads at h*20+s*4 are 16B-aligned and
// tile banks; sAtt stride 516 => h-groups land on distinct banks.
constexpr int S_QH = 20;
constexpr int S_BT = 20;
constexpr int S_AT = 516;

typedef _Float16 half2v __attribute__((ext_vector_type(2)));
typedef _Float16 half4v __attribute__((ext_vector_type(4)));
typedef float float4v __attribute__((ext_vector_type(4)));
typedef unsigned uint2v __attribute__((ext_vector_type(2)));

__device__ __forceinline__ float swishf(float x) {
    return x * __builtin_amdgcn_rcpf(1.0f + __expf(-x));
}

__device__ __forceinline__ unsigned pk16(float a, float b) {
    unsigned short ha = __builtin_bit_cast(unsigned short, (_Float16)a);
    unsigned short hb = __builtin_bit_cast(unsigned short, (_Float16)b);
    return (unsigned)ha | ((unsigned)hb << 16);
}

__device__ __forceinline__ unsigned pkrtz(float a, float b) {
    return __builtin_bit_cast(unsigned, __builtin_amdgcn_cvt_pkrtz(a, b));
}

__device__ __forceinline__ float4v mfma16(half4v a, half4v b, float4v c) {
    return __builtin_amdgcn_mfma_f32_16x16x16f16(a, b, c, 0, 0, 0);
}

// QKV projection, column-split: blocks 0..511 = (rowTile 0..255) x (colTile 0..1),
// 8 rows x 128 cols each -> 2 blocks/CU (total weight traffic unchanged vs
// 8x256 tiles; doubles TLP for the serial K-loop). Block 512 = mask decode.
__global__ __launch_bounds__(256) void k_qkvc(
    const float* __restrict__ x,
    const float* __restrict__ wq, const float* __restrict__ bq,
    const float* __restrict__ wk, const float* __restrict__ bk,
    const float* __restrict__ wv, const float* __restrict__ bv,
    unsigned* __restrict__ Qh, unsigned* __restrict__ Kh,
    unsigned* __restrict__ Vh,
    const unsigned char* __restrict__ mraw,
    int* __restrict__ list, int* __restrict__ meta) {
    const int t = threadIdx.x;

    if (blockIdx.x == 512) {
        __shared__ int s_isbool;
        if (t == 0) s_isbool = 0;
        __syncthreads();
        int found = 0;
        for (int i = t; i < kB * kN; i += 256)
            if ((i & 3) && mraw[i]) found = 1;
        if (found) atomicOr(&s_isbool, 1);
        __syncthreads();
        const int isb = s_isbool;
        const int b = t >> 6, lane = t & 63;
        const int* mi = (const int*)mraw;
        int base = 0;
        for (int c = 0; c < 8; ++c) {
            const int m = c * 64 + lane;
            const int idx = b * kN + m;
            const int valid = isb ? (mraw[idx] != 0) : (mi[idx] != 0);
            unsigned long long bal = __ballot(valid);
            int rank = (int)__popcll(bal & ((1ull << lane) - 1ull));
            if (valid) list[b * kN + base + rank] = m;
            base += (int)__popcll(bal);
        }
        for (int i = base + lane; i < kN; i += 64)
            list[b * kN + i] = (base == 0) ? i : 0;
        if (lane == 0) {
            meta[b] = (base == 0) ? kN : base;
            meta[4 + b] = (base == 0);
        }
        return;
    }

    __shared__ float sx[8][kC];
    const int r0 = (blockIdx.x >> 1) * 8;
    const int c0 = (blockIdx.x & 1) * 128;
    const int col = t & 127;       // adjacent lanes = adjacent cols (shfl pairing ok)
    const int g = t >> 7;          // row-group: rows r0 + g*4 + {0..3}
    #pragma unroll
    for (int r = 0; r < 8; ++r) sx[r][t] = x[(r0 + r) * kC + t];
    __syncthreads();
    float aq[4] = {}, ak[4] = {}, av[4] = {};
    for (int k = 0; k < kC; ++k) {
        const float q = wq[k * kC + c0 + col];
        const float kk = wk[k * kC + c0 + col];
        const float v = wv[k * kC + c0 + col];
        #pragma unroll
        for (int r = 0; r < 4; ++r) {
            const float xs = sx[g * 4 + r][k];
            aq[r] += xs * q;
            ak[r] += xs * kk;
            av[r] += xs * v;
        }
    }
    const float qb = bq[c0 + col], kb = bk[c0 + col], vb = bv[c0 + col];
    #pragma unroll
    for (int r = 0; r < 4; ++r) {
        const int row = r0 + g * 4 + r;
        const float qv = aq[r] + qb;
        const float kv = ak[r] + kb;
        const float vv = av[r] + vb;
        const float qn = __shfl_down(qv, 1);
        const float kn = __shfl_down(kv, 1);
        const float vn = __shfl_down(vv, 1);
        if ((t & 1) == 0) {
            const int ci = (c0 + col) >> 1;
            Qh[row * (kC / 2) + ci] = pk16(qv, qn);
            Kh[row * (kC / 2) + ci] = pk16(kv, kn);
            Vh[row * (kC / 2) + ci] = pk16(vv, vn);
        }
    }
}

// Fused attention, MFMA-based MLP over the compacted list. One block/(b,n).
// Transposed-operand scheme: Z^T = W^T @ X^T with v_mfma_f32_16x16x16f16
// (layouts verified: absmax stable at 1.95e-3 through r7).
// r8: 2 independent tile-chains per wave (A: tile, B: tile+4) -- r7 showed
// one serial mfma->swish->mfma chain per wave exposes full pipe latency
// (MfmaUtil 6.8%, VALUBusy 50%, dur 2x issue time). launch_bounds stays
// (256,4): VGPR cap 128 >> predicted ~110 (r5 lesson: never tighten the
// cap and grow live state together).
__global__ __launch_bounds__(256, 4) void k_attn(
    const float* __restrict__ G,
    const unsigned* __restrict__ Qh,
    const unsigned* __restrict__ Kh,
    const unsigned* __restrict__ Vh,
    const float* __restrict__ w1, const float* __restrict__ b1,
    const float* __restrict__ w2, const float* __restrict__ b2,
    const float* __restrict__ w3, const float* __restrict__ b3,
    const int* __restrict__ list, const int* __restrict__ meta,
    float* __restrict__ out) {
    __shared__ __align__(16) unsigned sQh[kH * S_QH];   // 640 B
    __shared__ __align__(16) uint4 sG4[kN];             // 8 KB packed f16 g
    __shared__ int sList[kN];                           // 2 KB
    __shared__ __align__(16) float sB1T[kH * S_BT];     // 640 B
    __shared__ __align__(16) float sB2T[kH * S_BT];
    __shared__ __align__(16) float sW3T[kH * S_BT];
    __shared__ float sB3[kH];
    __shared__ float sAtt[kH * S_AT];                   // 16.5 KB
    __shared__ float sInv[kH];

    const int bn = blockIdx.x;
    const int b = bn >> 9;
    const int t = threadIdx.x;
    const int l = t & 63;
    const int p = l & 15;        // pair-in-tile (mfma col)
    const int s = l >> 4;        // k-slice (mfma k-quarter)
    const int wid = t >> 6;      // wave 0..3

    // ---- A fragments: W1^T, W2^T in registers (prologue, L2-hot) ----
    half4v a1f[kH], a2f[kH];
    #pragma unroll
    for (int h = 0; h < kH; ++h) {
        #pragma unroll
        for (int r = 0; r < 4; ++r) {
            const int k = 4 * s + r;
            a1f[h][r] = (k < kDG) ? (_Float16)w1[(h * kDG + k) * kHID + p]
                                  : (_Float16)0.f;
            a2f[h][r] = (_Float16)w2[(h * kHID + k) * kHID + p];
        }
    }

    // ---- staging ----
    if (t < kH * S_QH) {
        const int hh = t / S_QH, r = t % S_QH;
        sQh[t] = (r < 16) ? Qh[bn * (kC / 2) + hh * 16 + r] : 0u;
    }
    sList[t] = list[b * kN + t];
    sList[t + 256] = list[b * kN + t + 256];
    #pragma unroll 1
    for (int rep = 0; rep < 2; ++rep) {
        const int m = t + rep * 256;
        const float* gp = G + ((size_t)bn * kN + m) * kDG;
        uint4 gw;
        gw.x = pkrtz(gp[0], gp[1]);
        gw.y = pkrtz(gp[2], gp[3]);
        gw.z = pkrtz(gp[4], gp[5]);
        gw.w = 0;
        sG4[m] = gw;
    }
    if (t < 128) {
        const int hh = t >> 4, j = t & 15;
        sB1T[hh * S_BT + j] = b1[hh * kHID + j];
        sB2T[hh * S_BT + j] = b2[hh * kHID + j];
        sW3T[hh * S_BT + j] = w3[hh * kHID + j];
        if (j == 0) sB3[hh] = b3[hh];
    }
    const int nv = meta[b];
    const int allm = meta[4 + b];
    __syncthreads();

    const unsigned* khB = Kh + (size_t)(b * kN) * (kC / 2);
    const int ntiles = (nv + 15) >> 4;

    // ---- per-head MLP + QK^T (h unrolled so a1f/a2f stay registers) ----
    #pragma unroll
    for (int h = 0; h < kH; ++h) {
        const float4v bv1 = *(const float4v*)&sB1T[h * S_BT + s * 4];
        const float4v bv2 = *(const float4v*)&sB2T[h * S_BT + s * 4];
        const float4v w3f = *(const float4v*)&sW3T[h * S_BT + s * 4];
        half4v w3h;
        #pragma unroll
        for (int r = 0; r < 4; ++r) w3h[r] = (_Float16)w3f[r];
        const float b3s = sB3[h];
        const float4v b3v = {b3s, b3s, b3s, b3s};
        // Q broadcast-A fragments (d halves 0/1)
        const uint2v q0u = {sQh[h * S_QH + 2 * s], sQh[h * S_QH + 2 * s + 1]};
        const uint2v q1u = {sQh[h * S_QH + 8 + 2 * s], sQh[h * S_QH + 9 + 2 * s]};
        const half4v qA0 = __builtin_bit_cast(half4v, q0u);
        const half4v qA1 = __builtin_bit_cast(half4v, q1u);

        #pragma unroll 1
        for (int tile = wid; tile < ntiles; tile += 8) {
            const int mcwA = tile * 16 + p;
            const int mcwB = mcwA + 64;            // (tile+4)*16 + p
            const int mcA = min(mcwA, nv - 1);
            const int mcB = min(mcwB, nv - 1);
            const int mA = sList[mcA];
            const int mB = sList[mcB];
            // K loads first (longest latency), both chains
            const unsigned* krA = khB + (size_t)mA * (kC / 2) + h * 16 + 2 * s;
            const unsigned* krB = khB + (size_t)mB * (kC / 2) + h * 16 + 2 * s;
            const uint2v k0A = {krA[0], krA[1]};
            const uint2v k1A = {krA[8], krA[9]};
            const uint2v k0B = {krB[0], krB[1]};
            const uint2v k1B = {krB[8], krB[9]};
            // G fragments
            const unsigned* gpA = (const unsigned*)&sG4[mA];
            const unsigned* gpB = (const unsigned*)&sG4[mB];
            uint2v guA = {gpA[(s & 1) * 2], gpA[(s & 1) * 2 + 1]};
            uint2v guB = {gpB[(s & 1) * 2], gpB[(s & 1) * 2 + 1]};
            if (s >= 2) { guA[0] = 0u; guA[1] = 0u; guB[0] = 0u; guB[1] = 0u; }
            const half4v bgA = __builtin_bit_cast(half4v, guA);
            const half4v bgB = __builtin_bit_cast(half4v, guB);
            // QK^T (independent of MLP chain)
            float4v caA = {0.f, 0.f, 0.f, 0.f};
            float4v caB = {0.f, 0.f, 0.f, 0.f};
            caA = mfma16(qA0, __builtin_bit_cast(half4v, k0A), caA);
            caB = mfma16(qA0, __builtin_bit_cast(half4v, k0B), caB);
            caA = mfma16(qA1, __builtin_bit_cast(half4v, k1A), caA);
            caB = mfma16(qA1, __builtin_bit_cast(half4v, k1B), caB);
            // layer 1 (bias as C-in), both chains interleaved
            const float4v c1A = mfma16(a1f[h], bgA, bv1);
            const float4v c1B = mfma16(a1f[h], bgB, bv1);
            const uint2v x1uA = {pkrtz(swishf(c1A[0]), swishf(c1A[1])),
                                 pkrtz(swishf(c1A[2]), swishf(c1A[3]))};
            const uint2v x1uB = {pkrtz(swishf(c1B[0]), swishf(c1B[1])),
                                 pkrtz(swishf(c1B[2]), swishf(c1B[3]))};
            // layer 2
            const float4v c2A = mfma16(a2f[h], __builtin_bit_cast(half4v, x1uA), bv2);
            const float4v c2B = mfma16(a2f[h], __builtin_bit_cast(half4v, x1uB), bv2);
            const uint2v x2uA = {pkrtz(swishf(c2A[0]), swishf(c2A[1])),
                                 pkrtz(swishf(c2A[2]), swishf(c2A[3]))};
            const uint2v x2uB = {pkrtz(swishf(c2B[0]), swishf(c2B[1])),
                                 pkrtz(swishf(c2B[2]), swishf(c2B[3]))};
            // layer 3: broadcast-A w3 -> every C row holds a3
            const float4v c3A = mfma16(w3h, __builtin_bit_cast(half4v, x2uA), b3v);
            const float4v c3B = mfma16(w3h, __builtin_bit_cast(half4v, x2uB), b3v);
            const float preA = swishf(c3A[0]) + caA[0] * 0.0625f;
            const float preB = swishf(c3B[0]) + caB[0] * 0.0625f;
            if (s == 0 && mcwA < nv) sAtt[h * S_AT + mcwA] = allm ? 0.f : preA;
            if (s == 0 && mcwB < nv) sAtt[h * S_AT + mcwB] = allm ? 0.f : preB;
        }
    }
    __syncthreads();

    // ---- per-head softmax over compacted range ----
    {
        const int hg = t >> 5;
        const int lane = t & 31;
        float mx = -3.4e38f;
        for (int idx = lane; idx < nv; idx += 32)
            mx = fmaxf(mx, sAtt[hg * S_AT + idx]);
        #pragma unroll
        for (int off = 16; off; off >>= 1)
            mx = fmaxf(mx, __shfl_xor(mx, off));
        float ls = 0.f;
        for (int idx = lane; idx < nv; idx += 32) {
            const float e = __expf(sAtt[hg * S_AT + idx] - mx);
            sAtt[hg * S_AT + idx] = e;
            ls += e;
        }
        #pragma unroll
        for (int off = 16; off; off >>= 1)
            ls += __shfl_xor(ls, off);
        if (lane == 0) sInv[hg] = 1.0f / ls;
    }
    __syncthreads();

    // ---- att @ V (V packed f16; thread = (head, d-pair, parity)) ----
    {
        const int hg = t >> 5;
        const int dp = (t >> 1) & 15;
        const int par = t & 1;
        const unsigned* vbp = Vh + (size_t)(b * kN) * (kC / 2) + hg * 16 + dp;
        float alo = 0.f, ahi = 0.f, blo = 0.f, bhi = 0.f;
        int mc = par;
        for (; mc + 2 < nv; mc += 4) {
            const float aw0 = sAtt[hg * S_AT + mc];
            const float aw1 = sAtt[hg * S_AT + mc + 2];
            const half2v v0 = __builtin_bit_cast(half2v, vbp[(size_t)sList[mc] * (kC / 2)]);
            const half2v v1 = __builtin_bit_cast(half2v, vbp[(size_t)sList[mc + 2] * (kC / 2)]);
            alo += aw0 * (float)v0[0];
            ahi += aw0 * (float)v0[1];
            blo += aw1 * (float)v1[0];
            bhi += aw1 * (float)v1[1];
        }
        for (; mc < nv; mc += 2) {
            const float aw = sAtt[hg * S_AT + mc];
            const half2v vv = __builtin_bit_cast(half2v, vbp[(size_t)sList[mc] * (kC / 2)]);
            alo += aw * (float)vv[0];
            ahi += aw * (float)vv[1];
        }
        alo += blo; ahi += bhi;
        alo += __shfl_xor(alo, 1);   // combine the two parities
        ahi += __shfl_xor(ahi, 1);
        out[bn * kC + t] = (par ? ahi : alo) * sInv[hg];
    }
}

// Final projection, column-split like k_qkvc: 512 blocks of 8 rows x 128 cols.
__global__ __launch_bounds__(256) void k_proj(
    const float* __restrict__ x,
    const float* __restrict__ w, const float* __restrict__ bias,
    float* __restrict__ y) {
    __shared__ float sx[8][kC];
    const int t = threadIdx.x;
    const int r0 = (blockIdx.x >> 1) * 8;
    const int c0 = (blockIdx.x & 1) * 128;
    const int col = t & 127;
    const int g = t >> 7;
    #pragma unroll
    for (int r = 0; r < 8; ++r) sx[r][t] = x[(r0 + r) * kC + t];
    __syncthreads();
    float acc[4] = {};
    for (int k = 0; k < kC; ++k) {
        const float wv = w[k * kC + c0 + col];
        #pragma unroll
        for (int r = 0; r < 4; ++r) acc[r] += sx[g * 4 + r][k] * wv;
    }
    const float bb = bias[c0 + col];
    #pragma unroll
    for (int r = 0; r < 4; ++r)
        y[(r0 + g * 4 + r) * kC + c0 + col] = acc[r] + bb;
}

}  // namespace

extern "C" void kernel_launch(void* const* d_in, const int* in_sizes, int n_in,
                              void* d_out, int out_size, void* d_ws, size_t ws_size,
                              hipStream_t stream) {
    (void)in_sizes; (void)n_in; (void)out_size; (void)ws_size;
    const float* G  = (const float*)d_in[0];
    const float* cf = (const float*)d_in[1];
    const float* wq = (const float*)d_in[2];
    const float* bq = (const float*)d_in[3];
    const float* wk = (const float*)d_in[4];
    const float* bk = (const float*)d_in[5];
    const float* wv = (const float*)d_in[6];   // in_w
    const float* bv = (const float*)d_in[7];   // in_b
    const float* wo = (const float*)d_in[8];   // out_w
    const float* bo = (const float*)d_in[9];   // out_b
    const float* w1 = (const float*)d_in[10];
    const float* b1 = (const float*)d_in[11];
    const float* w2 = (const float*)d_in[12];
    const float* b2 = (const float*)d_in[13];
    const float* w3 = (const float*)d_in[14];
    const float* b3 = (const float*)d_in[15];
    const unsigned char* mraw = (const unsigned char*)d_in[16];

    const int rows = kB * kN;  // 2048
    unsigned* Qh = (unsigned*)d_ws;                       // 1 MB
    unsigned* Kh = Qh + (size_t)rows * (kC / 2);          // 1 MB
    unsigned* Vh = Kh + (size_t)rows * (kC / 2);          // 1 MB
    float* O = (float*)(Vh + (size_t)rows * (kC / 2));    // 2 MB
    int* list = (int*)(O + (size_t)rows * kC);            // 8 KB
    int* meta = list + rows;                              // 32 B

    k_qkvc<<<513, 256, 0, stream>>>(cf, wq, bq, wk, bk, wv, bv,
                                    Qh, Kh, Vh, mraw, list, meta);
    k_attn<<<rows, 256, 0, stream>>>(G, Qh, Kh, Vh, w1, b1, w2, b2, w3, b3,
                                     list, meta, O);
    k_proj<<<512, 256, 0, stream>>>(O, wo, bo, (float*)d_out);
}